// Round 14
// baseline (237.887 us; speedup 1.0000x reference)
//
#include <hip/hip_runtime.h>

// Sub4BitLinear: y = X[M,K] @ W[N,K]^T, M=8192 N=4096 K=4096
// int8: (1) quant x -> i8 fragment-tiled + sx, (2) quant codebook W -> i8 + sw,
// (3) 128x256 i8 GEMM: A direct-from-global with DEPTH-2 register prefetch,
//     B double-buffered in 32 KiB LDS -> 2 blocks/CU, 1 barrier per K-tile.

#define M_DIM 8192
#define N_DIM 4096
#define K_DIM 4096
#define BK 64               // i8 K per tile = one mfma_i32_16x16x64 K-slab
#define NKT (K_DIM / BK)    // 64 K-tiles

typedef __attribute__((ext_vector_type(4))) int int32x4;

#define AS1 __attribute__((address_space(1)))
#define AS3 __attribute__((address_space(3)))

__device__ __forceinline__ void gl_lds16(const void* g, void* l) {
    __builtin_amdgcn_global_load_lds((const AS1 void*)g, (AS3 void*)l, 16, 0, 0);
}

// ---------------- kernel 1: per-row quantize x -> int8, fragment-tiled ----------------
// XQ layout: [mpanel(row/64)][kp(k/64)][mf(0..3)][lane(0..63)] x 16B.
__global__ __launch_bounds__(256) void quant_x(const float* __restrict__ X,
                                               char* __restrict__ XQ,
                                               float* __restrict__ SX) {
    const int row = blockIdx.x;
    const int t = threadIdx.x;           // k-chunk: bytes [16t, 16t+16)
    const float4* xp = (const float4*)(X + (size_t)row * K_DIM);
    float4 v[4];
    float mx = 0.0f;
#pragma unroll
    for (int i = 0; i < 4; ++i) {
        v[i] = xp[t * 4 + i];
        mx = fmaxf(mx, fmaxf(fmaxf(fabsf(v[i].x), fabsf(v[i].y)),
                             fmaxf(fabsf(v[i].z), fabsf(v[i].w))));
    }
#pragma unroll
    for (int off = 1; off < 64; off <<= 1)
        mx = fmaxf(mx, __shfl_xor(mx, off));
    __shared__ float wmx[4];
    if ((t & 63) == 0) wmx[t >> 6] = mx;
    __syncthreads();
    mx = fmaxf(fmaxf(wmx[0], wmx[1]), fmaxf(wmx[2], wmx[3]));
    const float inv = 127.0f / mx;
    int4 o4;
    int* po = (int*)&o4;
#pragma unroll
    for (int i = 0; i < 4; ++i) {
        int q0 = (int)rintf(v[i].x * inv);
        int q1 = (int)rintf(v[i].y * inv);
        int q2 = (int)rintf(v[i].z * inv);
        int q3 = (int)rintf(v[i].w * inv);
        po[i] = (q0 & 255) | ((q1 & 255) << 8) | ((q2 & 255) << 16) | ((q3 & 255) << 24);
    }
    const int mpanel = row >> 6, mf = (row >> 4) & 3, fr = row & 15;
    const int kp = t >> 2, kg = t & 3;
    ((int4*)XQ)[(size_t)mpanel * 16384 + kp * 256 + mf * 64 + kg * 16 + fr] = o4;
    if (t == 0) SX[row] = mx * (1.0f / 127.0f);
}

// ---------------- kernel 2: per-row quantize codebook W -> int8 (row-major) ----------------
__global__ __launch_bounds__(256) void quant_w(const int* __restrict__ CD,
                                               const float* __restrict__ G,
                                               char* __restrict__ WQ,
                                               float* __restrict__ SW) {
    const int o = blockIdx.x;
    __shared__ int gq[8];
    if (threadIdx.x == 0) {
        float g[8], mx = 0.0f;
#pragma unroll
        for (int j = 0; j < 8; ++j) { g[j] = G[o * 8 + j]; mx = fmaxf(mx, fabsf(g[j])); }
        mx = fmaxf(mx, 1e-20f);
        const float inv = 127.0f / mx;
        SW[o] = mx * (1.0f / 127.0f);
#pragma unroll
        for (int j = 0; j < 8; ++j) gq[j] = ((int)rintf(g[j] * inv)) & 255;
    }
    __syncthreads();
    const int4* cp = (const int4*)(CD + (size_t)o * K_DIM);
    int* wp = (int*)(WQ + (size_t)o * K_DIM);
#pragma unroll
    for (int r = 0; r < 4; ++r) {
        int idx = r * 256 + threadIdx.x;
        int4 c = cp[idx];
        wp[idx] = gq[c.x] | (gq[c.y] << 8) | (gq[c.z] << 16) | (gq[c.w] << 24);
    }
}

// ---------------- kernel 3: 128x256 i8 GEMM, A-direct depth-2 prefetch ----------------
// 512 threads = 8 waves (2M x 4N); per-wave 64x64 = acc[4][4] i32 (AGPR).
// A: fragment-tiled global loads into TWO named reg sets (faA even tiles,
//    faB odd) prefetched 2 tiles ahead -> load latency spans a full K-tile.
// B: Bs[2][256x64B] = 32 KiB LDS, swizzle slot^((row>>1)&3) (2-way free).
// Iter t: RD_B(4 ds_read; A already in regs -> first MFMA waits ~12cy) ->
// 16 MFMA -> fence -> LDA(t+2 -> same set just consumed, in-order-safe WAR)
// -> vmcnt(4) [FIFO: drains exactly {A(t+1),B(t+1)}, leaves A(t+2)] ->
// barrier -> STGB(t+2) into the buffer all waves finished reading (their
// MFMA data-deps drained the reads before the barrier).
__global__ __launch_bounds__(512, 4) void gemm8(const char* __restrict__ A,
                                                const char* __restrict__ B,
                                                const float* __restrict__ SX,
                                                const float* __restrict__ SW,
                                                float* __restrict__ C) {
    __shared__ char Bs[2][256 * 64];

    const int tid = threadIdx.x;
    const int lane = tid & 63;
    const int wid = tid >> 6;
    const int wm = wid >> 2;        // 0..1: wave's M half (64 rows)
    const int wn = wid & 3;         // 0..3: wave's N slice (64 cols)

    // XCD-bijective block swizzle (nwg = 1024, %8 == 0)
    int wg = blockIdx.x;
    wg = (wg & 7) * (gridDim.x >> 3) + (wg >> 3);
    const int ntn = N_DIM / 256;    // 16
    const int bm = (wg / ntn) * 128;
    const int bn = (wg % ntn) * 256;

    // B fragment read lane constants (byte units, 64-B rows):
    const int fr = lane & 15;
    const int g = lane >> 4;
    const int offk = fr * 64 + ((g ^ ((fr >> 1) & 3)) << 4);
    const int bwoff = wn * 4096;    // wave B row base

    // A: per-wave panel base (fragment-tiled): mpanel = bm/64 + wm
    const char* Apan = A + (size_t)((bm >> 6) + wm) * 262144 + lane * 16;

    // B staging: chunk c = tid; row = c>>2 (0..127), slot = (c&3)^((row>>1)&3)
    const int row0 = tid >> 2;
    const int sl = (((tid & 3) ^ ((row0 >> 1) & 3)) << 4);
    const char* gB0 = B + (size_t)(bn + row0) * K_DIM + sl;
    const char* gB1 = B + (size_t)(bn + 128 + row0) * K_DIM + sl;

#define KCL(KT) (((KT) < NKT) ? (KT) : 0)

#define STGB(BUF, KT) do {                                                         \
        const int kb_ = KCL(KT) * BK;                                              \
        gl_lds16(gB0 + kb_, &Bs[BUF][0] + wid * 1024);                             \
        gl_lds16(gB1 + kb_, &Bs[BUF][8192] + wid * 1024);                          \
    } while (0)

#define LDA(FA, KT) do {                                                           \
        const char* ap_ = Apan + (size_t)KCL(KT) * 4096;                           \
        FA[0] = *(const int32x4*)(ap_);                                            \
        FA[1] = *(const int32x4*)(ap_ + 1024);                                     \
        FA[2] = *(const int32x4*)(ap_ + 2048);                                     \
        FA[3] = *(const int32x4*)(ap_ + 3072);                                     \
    } while (0)

#define RD_B(BUF)                                                                  \
    _Pragma("unroll") for (int n = 0; n < 4; ++n)                                  \
        fb[n] = *(const int32x4*)&Bs[BUF][bwoff + n * 1024 + offk];

#define MF_ALL(FA)                                                                 \
    _Pragma("unroll") for (int m = 0; m < 4; ++m)                                  \
    _Pragma("unroll") for (int n = 0; n < 4; ++n)                                  \
        acc[m][n] = __builtin_amdgcn_mfma_i32_16x16x64_i8(FA[m], fb[n], acc[m][n], 0, 0, 0);

#define BODY(CUR, FA, KT) do {                                                     \
        RD_B(CUR)                                                                  \
        __builtin_amdgcn_s_setprio(1);                                             \
        MF_ALL(FA)                                                                 \
        __builtin_amdgcn_s_setprio(0);                                             \
        __builtin_amdgcn_sched_barrier(0);                                         \
        LDA(FA, (KT) + 2);                                                         \
        asm volatile("s_waitcnt vmcnt(4)" ::: "memory");                           \
        __builtin_amdgcn_s_barrier();                                              \
        STGB(CUR, (KT) + 2);                                                       \
    } while (0)

    int32x4 acc[4][4] = {};
    int32x4 faA[4], faB[4];
    int32x4 fb[4];

    // prologue: B(0)->Bs0, B(1)->Bs1, A(0)->faA, A(1)->faB.
    // FIFO [B0 2, B1 2, A0 4, A1 4]; vmcnt(4) drains B0,B1,A0; leaves A1.
    STGB(0, 0);
    STGB(1, 1);
    LDA(faA, 0);
    LDA(faB, 1);
    asm volatile("s_waitcnt vmcnt(4)" ::: "memory");
    __builtin_amdgcn_s_barrier();

    for (int j = 0; j < NKT / 2; ++j) {
        BODY(0, faA, 2 * j);
        BODY(1, faB, 2 * j + 1);
    }
    asm volatile("s_waitcnt vmcnt(0)" ::: "memory");

    // C-write with scales: row = (lane>>4)*4 + r, col = lane&15 per 16x16 frag
    const int crow0 = bm + wm * 64 + (g << 2);
    const int ccol0 = bn + wn * 64 + fr;
    float swc[4];
#pragma unroll
    for (int ni = 0; ni < 4; ++ni) swc[ni] = SW[ccol0 + ni * 16];
#pragma unroll
    for (int mi = 0; mi < 4; ++mi)
#pragma unroll
        for (int r = 0; r < 4; ++r) {
            const float sxr = SX[crow0 + mi * 16 + r];
#pragma unroll
            for (int ni = 0; ni < 4; ++ni)
                C[(size_t)(crow0 + mi * 16 + r) * N_DIM + ccol0 + ni * 16] =
                    (float)acc[mi][ni][r] * sxr * swc[ni];
        }
}

// ---------------- fallback: tiled f32 GEMM with on-the-fly dequant ----------------
__global__ __launch_bounds__(256) void fb_gemm(const float* __restrict__ X,
                                               const float* __restrict__ G,
                                               const int* __restrict__ CD,
                                               float* __restrict__ Y) {
    __shared__ float xs[16][64];
    __shared__ float ws[16][64];
    const int bm = blockIdx.y << 6, bn = blockIdx.x << 6;
    const int tid = threadIdx.x;
    const int tn = tid & 15, tm = tid >> 4;
    float acc[4][4] = {};
    for (int k0 = 0; k0 < K_DIM; k0 += 16) {
#pragma unroll
        for (int r = 0; r < 4; ++r) {
            int e = r * 256 + tid;
            int mm = e >> 4, kk = e & 15;
            xs[kk][mm] = X[(size_t)(bm + mm) * K_DIM + k0 + kk];
            int code = CD[(size_t)(bn + mm) * K_DIM + k0 + kk];
            ws[kk][mm] = G[(bn + mm) * 8 + code];
        }
        __syncthreads();
#pragma unroll
        for (int kk = 0; kk < 16; ++kk)
#pragma unroll
            for (int i = 0; i < 4; ++i)
#pragma unroll
                for (int j = 0; j < 4; ++j)
                    acc[i][j] += xs[kk][tm * 4 + i] * ws[kk][tn * 4 + j];
        __syncthreads();
    }
#pragma unroll
    for (int i = 0; i < 4; ++i)
#pragma unroll
        for (int j = 0; j < 4; ++j)
            Y[(size_t)(bm + tm * 4 + i) * N_DIM + bn + tn * 4 + j] = acc[i][j];
}

extern "C" void kernel_launch(void* const* d_in, const int* in_sizes, int n_in,
                              void* d_out, int out_size, void* d_ws, size_t ws_size,
                              hipStream_t stream) {
    const float* x = (const float*)d_in[0];
    const float* qg = (const float*)d_in[1];
    const int* wc = (const int*)d_in[2];
    float* y = (float*)d_out;

    // workspace: sx[8192] f32 | sw[4096] f32 | xq[8192*4096] i8 | wq[4096*4096] i8
    const size_t sx_off = 0;
    const size_t sw_off = (size_t)M_DIM * 4;
    const size_t xq_off = (size_t)(M_DIM + N_DIM) * 4;
    const size_t wq_off = xq_off + (size_t)M_DIM * K_DIM;
    const size_t need = wq_off + (size_t)N_DIM * K_DIM;

    if (ws_size >= need) {
        float* sx = (float*)((char*)d_ws + sx_off);
        float* sw = (float*)((char*)d_ws + sw_off);
        char* xq = (char*)d_ws + xq_off;
        char* wq = (char*)d_ws + wq_off;
        hipLaunchKernelGGL(quant_x, dim3(M_DIM), dim3(256), 0, stream, x, xq, sx);
        hipLaunchKernelGGL(quant_w, dim3(N_DIM), dim3(256), 0, stream, wc, qg, wq, sw);
        const int nwg = (M_DIM / 128) * (N_DIM / 256);   // 1024
        hipLaunchKernelGGL(gemm8, dim3(nwg), dim3(512), 0, stream,
                           xq, wq, sx, sw, y);
    } else {
        hipLaunchKernelGGL(fb_gemm, dim3(N_DIM / 64, M_DIM / 64), dim3(256), 0, stream,
                           x, qg, wc, y);
    }
}

// Round 15
// 205.233 us; speedup vs baseline: 1.1591x; 1.1591x over previous
//
#include <hip/hip_runtime.h>

// Sub4BitLinear: y = X[M,K] @ W[N,K]^T, M=8192 N=4096 K=4096
// int8: (1) per-row quant x -> i8 + sx, (2) per-row quant codebook W -> i8 + sw,
// (3) 256x128-tile 4-wave i8 GEMM, per-wave 128x64 output (high LDS reuse),
//     3-deep LDS ring (72 KiB) -> 2 blocks/CU, 1 barrier + counted vmcnt(6)/K-tile.

#define M_DIM 8192
#define N_DIM 4096
#define K_DIM 4096
#define BK 64               // i8 elements per K-tile (64 B/row)
#define NKT (K_DIM / BK)    // 64 K-tiles

typedef __attribute__((ext_vector_type(4))) int int32x4;

#define AS1 __attribute__((address_space(1)))
#define AS3 __attribute__((address_space(3)))

__device__ __forceinline__ void gl_lds16(const void* g, void* l) {
    __builtin_amdgcn_global_load_lds((const AS1 void*)g, (AS3 void*)l, 16, 0, 0);
}

// ---------------- kernel 1: per-row quantize x -> int8 (row-major) ----------------
__global__ __launch_bounds__(256) void quant_x(const float* __restrict__ X,
                                               char* __restrict__ XQ,
                                               float* __restrict__ SX) {
    const int row = blockIdx.x;
    const int t = threadIdx.x;
    const float4* xp = (const float4*)(X + (size_t)row * K_DIM);
    float4 v[4];
    float mx = 0.0f;
#pragma unroll
    for (int i = 0; i < 4; ++i) {
        v[i] = xp[t * 4 + i];
        mx = fmaxf(mx, fmaxf(fmaxf(fabsf(v[i].x), fabsf(v[i].y)),
                             fmaxf(fabsf(v[i].z), fabsf(v[i].w))));
    }
#pragma unroll
    for (int off = 1; off < 64; off <<= 1)
        mx = fmaxf(mx, __shfl_xor(mx, off));
    __shared__ float wmx[4];
    if ((t & 63) == 0) wmx[t >> 6] = mx;
    __syncthreads();
    mx = fmaxf(fmaxf(wmx[0], wmx[1]), fmaxf(wmx[2], wmx[3]));
    const float inv = 127.0f / mx;
    int4 o4;
    int* po = (int*)&o4;
#pragma unroll
    for (int i = 0; i < 4; ++i) {
        int q0 = (int)rintf(v[i].x * inv);
        int q1 = (int)rintf(v[i].y * inv);
        int q2 = (int)rintf(v[i].z * inv);
        int q3 = (int)rintf(v[i].w * inv);
        po[i] = (q0 & 255) | ((q1 & 255) << 8) | ((q2 & 255) << 16) | ((q3 & 255) << 24);
    }
    ((int4*)(XQ + (size_t)row * K_DIM))[t] = o4;
    if (t == 0) SX[row] = mx * (1.0f / 127.0f);
}

// ---------------- kernel 2: per-row quantize codebook W -> int8 ----------------
__global__ __launch_bounds__(256) void quant_w(const int* __restrict__ CD,
                                               const float* __restrict__ G,
                                               char* __restrict__ WQ,
                                               float* __restrict__ SW) {
    const int o = blockIdx.x;
    __shared__ int gq[8];
    if (threadIdx.x == 0) {
        float g[8], mx = 0.0f;
#pragma unroll
        for (int j = 0; j < 8; ++j) { g[j] = G[o * 8 + j]; mx = fmaxf(mx, fabsf(g[j])); }
        mx = fmaxf(mx, 1e-20f);
        const float inv = 127.0f / mx;
        SW[o] = mx * (1.0f / 127.0f);
#pragma unroll
        for (int j = 0; j < 8; ++j) gq[j] = ((int)rintf(g[j] * inv)) & 255;
    }
    __syncthreads();
    const int4* cp = (const int4*)(CD + (size_t)o * K_DIM);
    int* wp = (int*)(WQ + (size_t)o * K_DIM);
#pragma unroll
    for (int r = 0; r < 4; ++r) {
        int idx = r * 256 + threadIdx.x;
        int4 c = cp[idx];
        wp[idx] = gq[c.x] | (gq[c.y] << 8) | (gq[c.z] << 16) | (gq[c.w] << 24);
    }
}

// ---------------- kernel 3: 256x128 4-wave i8 GEMM, 3-deep ring ----------------
// 256 threads = 4 waves (2M x 2N); per-wave 128x64 = acc[8][4] i32 (AGPR).
// LDS: As[3][256x64B]=48K + Bs[3][128x64B]=24K = 72 KiB -> 2 blocks/CU.
// LDS/CU-pair-K-tile = 144 KB = 1125 cy < MFMA 1306 cy -> MFMA-bound.
// Swizzle (64B rows, 4 slots): slot ^= (row>>1)&3 -> 2-way (free).
// Body t: STG(t+2 -> buf (t+2)%3, holds t-1 which finished at barrier t-1)
//   | RD_B,RD_A from buf t%3 (compiler counted-lgkm overlaps under MFMA)
//   | 32 MFMA | vmcnt(6) (in-flight 12 = {t+1,t+2} -> drains t+1) | barrier.
// Tail t>=62: kt clamped, garbage lands in buffers never read again.
__global__ __launch_bounds__(256, 2) void gemm3(const char* __restrict__ A,
                                                const char* __restrict__ B,
                                                const float* __restrict__ SX,
                                                const float* __restrict__ SW,
                                                float* __restrict__ C) {
    __shared__ char As[3][256 * 64];
    __shared__ char Bs[3][128 * 64];

    const int tid = threadIdx.x;
    const int lane = tid & 63;
    const int wid = tid >> 6;       // 0..3
    const int wm = wid >> 1;        // 0..1: wave's M half (128 rows)
    const int wn = wid & 1;         // 0..1: wave's N half (64 cols)

    // XCD-bijective block swizzle (nwg = 1024, %8 == 0)
    int wg = blockIdx.x;
    wg = (wg & 7) * (gridDim.x >> 3) + (wg >> 3);
    const int ntn = N_DIM / 128;    // 32
    const int bm = (wg / ntn) * 256;
    const int bn = (wg % ntn) * 128;

    // fragment read lane constants (byte units, 64-B rows):
    const int fr = lane & 15;
    const int g = lane >> 4;
    const int offk = fr * 64 + ((g ^ ((fr >> 1) & 3)) << 4);
    const int awoff = wm * 8192;    // wave A row base (128 rows * 64 B)
    const int bwoff = wn * 4096;    // wave B row base (64 rows * 64 B)

    // staging: chunk c = q*256+tid; row = c>>2, slot = (c&3)^((row>>1)&3)
    // (q*64 row offsets preserve the XOR since 64 % 8 == 0)
    const int row0 = tid >> 2;      // 0..63
    const int sl = (((tid & 3) ^ ((row0 >> 1) & 3)) << 4);
    const char* gA0 = A + (size_t)(bm + row0) * K_DIM + sl;
    const char* gA1 = A + (size_t)(bm + 64 + row0) * K_DIM + sl;
    const char* gA2 = A + (size_t)(bm + 128 + row0) * K_DIM + sl;
    const char* gA3 = A + (size_t)(bm + 192 + row0) * K_DIM + sl;
    const char* gB0 = B + (size_t)(bn + row0) * K_DIM + sl;
    const char* gB1 = B + (size_t)(bn + 64 + row0) * K_DIM + sl;

#define KCL(KT) (((KT) < NKT) ? (KT) : 0)

#define STG(BUF, KT) do {                                                          \
        const int kb_ = KCL(KT) * BK;                                              \
        gl_lds16(gA0 + kb_, &As[BUF][0] + tid * 16);                               \
        gl_lds16(gA1 + kb_, &As[BUF][4096] + tid * 16);                            \
        gl_lds16(gA2 + kb_, &As[BUF][8192] + tid * 16);                            \
        gl_lds16(gA3 + kb_, &As[BUF][12288] + tid * 16);                           \
        gl_lds16(gB0 + kb_, &Bs[BUF][0] + tid * 16);                               \
        gl_lds16(gB1 + kb_, &Bs[BUF][4096] + tid * 16);                            \
    } while (0)

#define RD_B(CUR)                                                                  \
    _Pragma("unroll") for (int n = 0; n < 4; ++n)                                  \
        fb[n] = *(const int32x4*)&Bs[CUR][bwoff + n * 1024 + offk];

#define RD_A(CUR)                                                                  \
    _Pragma("unroll") for (int m = 0; m < 8; ++m)                                  \
        fa[m] = *(const int32x4*)&As[CUR][awoff + m * 1024 + offk];

#define MF_ALL                                                                     \
    _Pragma("unroll") for (int m = 0; m < 8; ++m)                                  \
    _Pragma("unroll") for (int n = 0; n < 4; ++n)                                  \
        acc[m][n] = __builtin_amdgcn_mfma_i32_16x16x64_i8(fa[m], fb[n], acc[m][n], 0, 0, 0);

#define BODY(CUR, NXT2, T) do {                                                    \
        STG(NXT2, (T) + 2);                                                        \
        RD_B(CUR) RD_A(CUR)                                                        \
        __builtin_amdgcn_s_setprio(1);                                             \
        MF_ALL                                                                     \
        __builtin_amdgcn_s_setprio(0);                                             \
        __builtin_amdgcn_sched_barrier(0);                                         \
        asm volatile("s_waitcnt vmcnt(6)" ::: "memory");                           \
        __builtin_amdgcn_s_barrier();                                              \
    } while (0)

    int32x4 acc[8][4] = {};
    int32x4 fa[8];
    int32x4 fb[4];

    // prologue: stage tiles 0,1; vmcnt(6) drains tile 0 (12 in flight); barrier.
    STG(0, 0);
    STG(1, 1);
    asm volatile("s_waitcnt vmcnt(6)" ::: "memory");
    __builtin_amdgcn_s_barrier();

    // t = 0..62 in static %3 triples; t=63 separate (63 = 3*21).
    for (int j = 0; j < 21; ++j) {
        const int t = 3 * j;
        BODY(0, 2, t);
        BODY(1, 0, t + 1);
        BODY(2, 1, t + 2);
    }
    BODY(0, 2, 63);
    asm volatile("s_waitcnt vmcnt(0)" ::: "memory");

    // C-write with scales: row = (lane>>4)*4 + r, col = lane&15 per 16x16 frag
    const int crow0 = bm + wm * 128 + (g << 2);
    const int ccol0 = bn + wn * 64 + fr;
    float swc[4];
#pragma unroll
    for (int ni = 0; ni < 4; ++ni) swc[ni] = SW[ccol0 + ni * 16];
#pragma unroll
    for (int mi = 0; mi < 8; ++mi)
#pragma unroll
        for (int r = 0; r < 4; ++r) {
            const float sxr = SX[crow0 + mi * 16 + r];
#pragma unroll
            for (int ni = 0; ni < 4; ++ni)
                C[(size_t)(crow0 + mi * 16 + r) * N_DIM + ccol0 + ni * 16] =
                    (float)acc[mi][ni][r] * sxr * swc[ni];
        }
}

// ---------------- fallback: tiled f32 GEMM with on-the-fly dequant ----------------
__global__ __launch_bounds__(256) void fb_gemm(const float* __restrict__ X,
                                               const float* __restrict__ G,
                                               const int* __restrict__ CD,
                                               float* __restrict__ Y) {
    __shared__ float xs[16][64];
    __shared__ float ws[16][64];
    const int bm = blockIdx.y << 6, bn = blockIdx.x << 6;
    const int tid = threadIdx.x;
    const int tn = tid & 15, tm = tid >> 4;
    float acc[4][4] = {};
    for (int k0 = 0; k0 < K_DIM; k0 += 16) {
#pragma unroll
        for (int r = 0; r < 4; ++r) {
            int e = r * 256 + tid;
            int mm = e >> 4, kk = e & 15;
            xs[kk][mm] = X[(size_t)(bm + mm) * K_DIM + k0 + kk];
            int code = CD[(size_t)(bn + mm) * K_DIM + k0 + kk];
            ws[kk][mm] = G[(bn + mm) * 8 + code];
        }
        __syncthreads();
#pragma unroll
        for (int kk = 0; kk < 16; ++kk)
#pragma unroll
            for (int i = 0; i < 4; ++i)
#pragma unroll
                for (int j = 0; j < 4; ++j)
                    acc[i][j] += xs[kk][tm * 4 + i] * ws[kk][tn * 4 + j];
        __syncthreads();
    }
#pragma unroll
    for (int i = 0; i < 4; ++i)
#pragma unroll
        for (int j = 0; j < 4; ++j)
            Y[(size_t)(bm + tm * 4 + i) * N_DIM + bn + tn * 4 + j] = acc[i][j];
}

extern "C" void kernel_launch(void* const* d_in, const int* in_sizes, int n_in,
                              void* d_out, int out_size, void* d_ws, size_t ws_size,
                              hipStream_t stream) {
    const float* x = (const float*)d_in[0];
    const float* qg = (const float*)d_in[1];
    const int* wc = (const int*)d_in[2];
    float* y = (float*)d_out;

    // workspace: sx[8192] f32 | sw[4096] f32 | xq[8192*4096] i8 | wq[4096*4096] i8
    const size_t sx_off = 0;
    const size_t sw_off = (size_t)M_DIM * 4;
    const size_t xq_off = (size_t)(M_DIM + N_DIM) * 4;
    const size_t wq_off = xq_off + (size_t)M_DIM * K_DIM;
    const size_t need = wq_off + (size_t)N_DIM * K_DIM;

    if (ws_size >= need) {
        float* sx = (float*)((char*)d_ws + sx_off);
        float* sw = (float*)((char*)d_ws + sw_off);
        char* xq = (char*)d_ws + xq_off;
        char* wq = (char*)d_ws + wq_off;
        hipLaunchKernelGGL(quant_x, dim3(M_DIM), dim3(256), 0, stream, x, xq, sx);
        hipLaunchKernelGGL(quant_w, dim3(N_DIM), dim3(256), 0, stream, wc, qg, wq, sw);
        const int nwg = (M_DIM / 256) * (N_DIM / 128);   // 1024
        hipLaunchKernelGGL(gemm3, dim3(nwg), dim3(256), 0, stream,
                           xq, wq, sx, sw, y);
    } else {
        hipLaunchKernelGGL(fb_gemm, dim3(N_DIM / 64, M_DIM / 64), dim3(256), 0, stream,
                           x, qg, wc, y);
    }
}

// Round 16
// 198.299 us; speedup vs baseline: 1.1996x; 1.0350x over previous
//
#include <hip/hip_runtime.h>

// Sub4BitLinear: y = X[M,K] @ W[N,K]^T, M=8192 N=4096 K=4096
// int8: (1) per-row quant x -> i8 + sx, (2) per-row quant codebook W -> i8 + sw,
// (3) 256x256-tile 8-wave i8 GEMM, BK=64, 4-buffer LDS ring (128 KiB),
//     ONE barrier + cheap vmcnt(0) per tile-pair; per-tile sched fences only.

#define M_DIM 8192
#define N_DIM 4096
#define K_DIM 4096
#define BK 64               // i8 elements per K-tile (64 B/row)
#define NKT (K_DIM / BK)    // 64 K-tiles

typedef __attribute__((ext_vector_type(4))) int int32x4;

#define AS1 __attribute__((address_space(1)))
#define AS3 __attribute__((address_space(3)))

__device__ __forceinline__ void gl_lds16(const void* g, void* l) {
    __builtin_amdgcn_global_load_lds((const AS1 void*)g, (AS3 void*)l, 16, 0, 0);
}

// ---------------- kernel 1: per-row quantize x -> int8 (row-major) ----------------
__global__ __launch_bounds__(256) void quant_x(const float* __restrict__ X,
                                               char* __restrict__ XQ,
                                               float* __restrict__ SX) {
    const int row = blockIdx.x;
    const int t = threadIdx.x;
    const float4* xp = (const float4*)(X + (size_t)row * K_DIM);
    float4 v[4];
    float mx = 0.0f;
#pragma unroll
    for (int i = 0; i < 4; ++i) {
        v[i] = xp[t * 4 + i];
        mx = fmaxf(mx, fmaxf(fmaxf(fabsf(v[i].x), fabsf(v[i].y)),
                             fmaxf(fabsf(v[i].z), fabsf(v[i].w))));
    }
#pragma unroll
    for (int off = 1; off < 64; off <<= 1)
        mx = fmaxf(mx, __shfl_xor(mx, off));
    __shared__ float wmx[4];
    if ((t & 63) == 0) wmx[t >> 6] = mx;
    __syncthreads();
    mx = fmaxf(fmaxf(wmx[0], wmx[1]), fmaxf(wmx[2], wmx[3]));
    const float inv = 127.0f / mx;
    int4 o4;
    int* po = (int*)&o4;
#pragma unroll
    for (int i = 0; i < 4; ++i) {
        int q0 = (int)rintf(v[i].x * inv);
        int q1 = (int)rintf(v[i].y * inv);
        int q2 = (int)rintf(v[i].z * inv);
        int q3 = (int)rintf(v[i].w * inv);
        po[i] = (q0 & 255) | ((q1 & 255) << 8) | ((q2 & 255) << 16) | ((q3 & 255) << 24);
    }
    ((int4*)(XQ + (size_t)row * K_DIM))[t] = o4;
    if (t == 0) SX[row] = mx * (1.0f / 127.0f);
}

// ---------------- kernel 2: per-row quantize codebook W -> int8 ----------------
__global__ __launch_bounds__(256) void quant_w(const int* __restrict__ CD,
                                               const float* __restrict__ G,
                                               char* __restrict__ WQ,
                                               float* __restrict__ SW) {
    const int o = blockIdx.x;
    __shared__ int gq[8];
    if (threadIdx.x == 0) {
        float g[8], mx = 0.0f;
#pragma unroll
        for (int j = 0; j < 8; ++j) { g[j] = G[o * 8 + j]; mx = fmaxf(mx, fabsf(g[j])); }
        mx = fmaxf(mx, 1e-20f);
        const float inv = 127.0f / mx;
        SW[o] = mx * (1.0f / 127.0f);
#pragma unroll
        for (int j = 0; j < 8; ++j) gq[j] = ((int)rintf(g[j] * inv)) & 255;
    }
    __syncthreads();
    const int4* cp = (const int4*)(CD + (size_t)o * K_DIM);
    int* wp = (int*)(WQ + (size_t)o * K_DIM);
#pragma unroll
    for (int r = 0; r < 4; ++r) {
        int idx = r * 256 + threadIdx.x;
        int4 c = cp[idx];
        wp[idx] = gq[c.x] | (gq[c.y] << 8) | (gq[c.z] << 16) | (gq[c.w] << 24);
    }
}

// ---------------- kernel 3: 256x256 8-wave i8 GEMM, 4-buffer ring ----------------
// 512 threads = 8 waves (2M x 4N); per-wave 128x64 = acc[8][4] i32 (128 AGPR).
// LDS: As[4][256x64B] + Bs[4][256x64B] = 128 KiB; 1 block/CU, 2 waves/SIMD.
// Swizzle (64-B rows, 4 slots): slot ^= (row>>1)&3 (2-way, free; measured 0).
// Pair j (tiles 2j,2j+1 in bufs {0,1} or {2,3}): [STG pair j+1 (8 loads)]
// [TILE a: 12 reads B-first + 32 MFMA + sched fence] [TILE b: same]
// [vmcnt(0) -- drains pair j+1, issued ~3000 cy earlier, ~free] [barrier].
// Waves desync inside the pair (only 1 barrier); sibling wave's MFMAs fill
// this wave's lgkm waits. Per-tile sched_barrier(0) bounds live frags to 12.
// Hazards: STG targets = pair j-1 bufs (reads done before prev barrier);
// reads target bufs published by the previous vmcnt+barrier; tail clamps kt.
__global__ __launch_bounds__(512, 2) void gemm4(const char* __restrict__ A,
                                                const char* __restrict__ B,
                                                const float* __restrict__ SX,
                                                const float* __restrict__ SW,
                                                float* __restrict__ C) {
    __shared__ char As[4][256 * 64];
    __shared__ char Bs[4][256 * 64];

    const int tid = threadIdx.x;
    const int lane = tid & 63;
    const int wid = tid >> 6;
    const int wm = wid >> 2;        // 0..1: wave's M half (128 rows)
    const int wn = wid & 3;         // 0..3: wave's N slice (64 cols)

    // XCD-bijective block swizzle (nwg = 512, %8 == 0)
    int wg = blockIdx.x;
    wg = (wg & 7) * (gridDim.x >> 3) + (wg >> 3);
    const int ntn = N_DIM / 256;    // 16
    const int bm = (wg / ntn) * 256;
    const int bn = (wg % ntn) * 256;

    // fragment read lane constants (byte units, 64-B rows):
    const int fr = lane & 15;
    const int g = lane >> 4;
    const int offk = fr * 64 + ((g ^ ((fr >> 1) & 3)) << 4);
    const int awoff = wm * 8192;    // wave A row base (128 rows * 64 B)
    const int bwoff = wn * 4096;    // wave B row base (64 rows * 64 B)

    // staging: chunk c = tid; row = c>>2 (0..127), slot = (c&3)^((row>>1)&3)
    const int row0 = tid >> 2;
    const int sl = (((tid & 3) ^ ((row0 >> 1) & 3)) << 4);
    const char* gA0 = A + (size_t)(bm + row0) * K_DIM + sl;
    const char* gA1 = A + (size_t)(bm + 128 + row0) * K_DIM + sl;
    const char* gB0 = B + (size_t)(bn + row0) * K_DIM + sl;
    const char* gB1 = B + (size_t)(bn + 128 + row0) * K_DIM + sl;

#define KCL(KT) (((KT) < NKT) ? (KT) : 0)

#define STG(BUF, KT) do {                                                          \
        const int kb_ = KCL(KT) * BK;                                              \
        gl_lds16(gA0 + kb_, &As[BUF][0] + wid * 1024);                             \
        gl_lds16(gA1 + kb_, &As[BUF][8192] + wid * 1024);                          \
        gl_lds16(gB0 + kb_, &Bs[BUF][0] + wid * 1024);                             \
        gl_lds16(gB1 + kb_, &Bs[BUF][8192] + wid * 1024);                          \
    } while (0)

#define RD_B(BUF)                                                                  \
    _Pragma("unroll") for (int n = 0; n < 4; ++n)                                  \
        fb[n] = *(const int32x4*)&Bs[BUF][bwoff + n * 1024 + offk];

#define RD_A(BUF)                                                                  \
    _Pragma("unroll") for (int m = 0; m < 8; ++m)                                  \
        fa[m] = *(const int32x4*)&As[BUF][awoff + m * 1024 + offk];

#define MF_ALL                                                                     \
    _Pragma("unroll") for (int m = 0; m < 8; ++m)                                  \
    _Pragma("unroll") for (int n = 0; n < 4; ++n)                                  \
        acc[m][n] = __builtin_amdgcn_mfma_i32_16x16x64_i8(fa[m], fb[n], acc[m][n], 0, 0, 0);

#define TILE(BUF) do {                                                             \
        RD_B(BUF) RD_A(BUF)                                                        \
        __builtin_amdgcn_s_setprio(1);                                             \
        MF_ALL                                                                     \
        __builtin_amdgcn_s_setprio(0);                                             \
        __builtin_amdgcn_sched_barrier(0);                                         \
    } while (0)

#define PAIR_END                                                                   \
    asm volatile("s_waitcnt vmcnt(0)" ::: "memory");                               \
    __builtin_amdgcn_s_barrier();

    int32x4 acc[8][4] = {};
    int32x4 fa[8];
    int32x4 fb[4];

    // prologue: stage pair 0 (tiles 0,1 -> bufs 0,1); drain; barrier.
    STG(0, 0);
    STG(1, 1);
    PAIR_END

    for (int jj = 0; jj < 16; ++jj) {
        const int t0 = 4 * jj;
        // even pair: compute tiles t0,t0+1 (bufs 0,1); stage t0+2,t0+3 -> bufs 2,3
        STG(2, t0 + 2);
        STG(3, t0 + 3);
        TILE(0);
        TILE(1);
        PAIR_END
        // odd pair: compute tiles t0+2,t0+3 (bufs 2,3); stage t0+4,t0+5 -> bufs 0,1
        STG(0, t0 + 4);
        STG(1, t0 + 5);
        TILE(2);
        TILE(3);
        PAIR_END
    }

    // C-write with scales: row = (lane>>4)*4 + r, col = lane&15 per 16x16 frag
    const int crow0 = bm + wm * 128 + (g << 2);
    const int ccol0 = bn + wn * 64 + fr;
    float swc[4];
#pragma unroll
    for (int ni = 0; ni < 4; ++ni) swc[ni] = SW[ccol0 + ni * 16];
#pragma unroll
    for (int mi = 0; mi < 8; ++mi)
#pragma unroll
        for (int r = 0; r < 4; ++r) {
            const float sxr = SX[crow0 + mi * 16 + r];
#pragma unroll
            for (int ni = 0; ni < 4; ++ni)
                C[(size_t)(crow0 + mi * 16 + r) * N_DIM + ccol0 + ni * 16] =
                    (float)acc[mi][ni][r] * sxr * swc[ni];
        }
}

// ---------------- fallback: tiled f32 GEMM with on-the-fly dequant ----------------
__global__ __launch_bounds__(256) void fb_gemm(const float* __restrict__ X,
                                               const float* __restrict__ G,
                                               const int* __restrict__ CD,
                                               float* __restrict__ Y) {
    __shared__ float xs[16][64];
    __shared__ float ws[16][64];
    const int bm = blockIdx.y << 6, bn = blockIdx.x << 6;
    const int tid = threadIdx.x;
    const int tn = tid & 15, tm = tid >> 4;
    float acc[4][4] = {};
    for (int k0 = 0; k0 < K_DIM; k0 += 16) {
#pragma unroll
        for (int r = 0; r < 4; ++r) {
            int e = r * 256 + tid;
            int mm = e >> 4, kk = e & 15;
            xs[kk][mm] = X[(size_t)(bm + mm) * K_DIM + k0 + kk];
            int code = CD[(size_t)(bn + mm) * K_DIM + k0 + kk];
            ws[kk][mm] = G[(bn + mm) * 8 + code];
        }
        __syncthreads();
#pragma unroll
        for (int kk = 0; kk < 16; ++kk)
#pragma unroll
            for (int i = 0; i < 4; ++i)
#pragma unroll
                for (int j = 0; j < 4; ++j)
                    acc[i][j] += xs[kk][tm * 4 + i] * ws[kk][tn * 4 + j];
        __syncthreads();
    }
#pragma unroll
    for (int i = 0; i < 4; ++i)
#pragma unroll
        for (int j = 0; j < 4; ++j)
            Y[(size_t)(bm + tm * 4 + i) * N_DIM + bn + tn * 4 + j] = acc[i][j];
}

extern "C" void kernel_launch(void* const* d_in, const int* in_sizes, int n_in,
                              void* d_out, int out_size, void* d_ws, size_t ws_size,
                              hipStream_t stream) {
    const float* x = (const float*)d_in[0];
    const float* qg = (const float*)d_in[1];
    const int* wc = (const int*)d_in[2];
    float* y = (float*)d_out;

    // workspace: sx[8192] f32 | sw[4096] f32 | xq[8192*4096] i8 | wq[4096*4096] i8
    const size_t sx_off = 0;
    const size_t sw_off = (size_t)M_DIM * 4;
    const size_t xq_off = (size_t)(M_DIM + N_DIM) * 4;
    const size_t wq_off = xq_off + (size_t)M_DIM * K_DIM;
    const size_t need = wq_off + (size_t)N_DIM * K_DIM;

    if (ws_size >= need) {
        float* sx = (float*)((char*)d_ws + sx_off);
        float* sw = (float*)((char*)d_ws + sw_off);
        char* xq = (char*)d_ws + xq_off;
        char* wq = (char*)d_ws + wq_off;
        hipLaunchKernelGGL(quant_x, dim3(M_DIM), dim3(256), 0, stream, x, xq, sx);
        hipLaunchKernelGGL(quant_w, dim3(N_DIM), dim3(256), 0, stream, wc, qg, wq, sw);
        const int nwg = (M_DIM / 256) * (N_DIM / 256);   // 512
        hipLaunchKernelGGL(gemm4, dim3(nwg), dim3(512), 0, stream,
                           xq, wq, sx, sw, y);
    } else {
        hipLaunchKernelGGL(fb_gemm, dim3(N_DIM / 64, M_DIM / 64), dim3(256), 0, stream,
                           x, qg, wc, y);
    }
}